// Round 2
// baseline (5063.129 us; speedup 1.0000x reference)
//
#include <hip/hip_runtime.h>

// Problem constants
#define BB   32    // batch
#define NN   512   // nodes
#define SS   64    // seq len / hidden S
#define WGPB 16    // workgroups per batch
#define TPB  512   // threads per workgroup
#define NPW  32    // n-values owned per workgroup (NN / WGPB)
#define EPT  4     // E_h values held per thread (SS / (TPB/NPW))
#define GRID (BB*WGPB)

__device__ __forceinline__ float rcp_fast(float x) { return __builtin_amdgcn_rcpf(x); }

// Persistent cooperative kernel: runs the whole 64-step scan.
// Per-batch sync via monotonic atomic counters (release/acquire, agent scope);
// s double-buffered by step parity.
__global__ void __launch_bounds__(TPB, 4)
spatial_attn_kernel(const float* __restrict__ gin,    // [B,N,S]
                    const float* __restrict__ hid,    // [B,S,N]
                    const float* __restrict__ v,      // [S]
                    const float* __restrict__ attn0,  // [B,N]
                    const float* __restrict__ W,      // [N,S]
                    const float* __restrict__ bias,   // [S]
                    float* __restrict__ out,          // [S,B,N]
                    float* __restrict__ s_buf,        // [2][B][N]
                    float* __restrict__ y_part,       // [B][WGPB][S]
                    unsigned int* __restrict__ cnt)   // [B] zeroed before launch
{
    const int wg  = blockIdx.x;
    const int b   = wg / WGPB;
    const int wgi = wg % WGPB;
    const int t   = threadIdx.x;
    const int nl  = t >> 4;          // 0..31  n-local
    const int sg  = t & 15;          // 0..15  s-group
    const int n   = wgi * NPW + nl;  // owned n for heavy phase
    const int s0  = sg * EPT;

    __shared__ float v_lds[SS];
    __shared__ float ey_lds[SS];
    __shared__ float x_own[NPW];
    __shared__ float yred[8 * SS];
    __shared__ float wred[8];
    __shared__ float wred2[8];

    if (t < SS) v_lds[t] = v[t];

    // Step-invariant: E_h = exp(2*H), kept in registers for all 64 steps.
    float eh[EPT];
#pragma unroll
    for (int j = 0; j < EPT; ++j)
        eh[j] = __expf(2.0f * hid[b * SS * NN + (s0 + j) * NN + n]);

    __syncthreads();
    float vsum = 0.f;
#pragma unroll
    for (int k = 0; k < SS; ++k) vsum += v_lds[k];
    const float SCONST = (float)SS * vsum;   // S * sum_k v_k

    const int lane = t & 63;
    const int wv   = t >> 6;  // wave id 0..7
    unsigned int bar = 0;

    for (int step = 0; step < SS; ++step) {
        // ---------- phase A: attn (softmax of prev s), x, out ----------
        float a;
        if (step == 0) {
            a = attn0[b * NN + t];           // initial attention state, used as-is
        } else {
            float sv = s_buf[((step - 1) & 1) * BB * NN + b * NN + t];
            float m = sv;
#pragma unroll
            for (int off = 1; off < 64; off <<= 1)
                m = fmaxf(m, __shfl_xor(m, off));
            if (lane == 0) wred[wv] = m;
            __syncthreads();
            m = wred[0];
#pragma unroll
            for (int w2 = 1; w2 < 8; ++w2) m = fmaxf(m, wred[w2]);
            float e = __expf(sv - m);
            float ss = e;
#pragma unroll
            for (int off = 1; off < 64; off <<= 1)
                ss += __shfl_xor(ss, off);
            if (lane == 0) wred2[wv] = ss;
            __syncthreads();
            float tot = wred2[0];
#pragma unroll
            for (int w2 = 1; w2 < 8; ++w2) tot += wred2[w2];
            a = e / tot;
        }
        // x for the 32 owned n (thread t computed a for n==t)
        if ((t >> 5) == wgi) {
            float inp = gin[b * NN * SS + t * SS + step];
            float x = a * inp;
            x_own[t & 31] = x;
            out[step * BB * NN + b * NN + t] = x;   // outs[t] = x before attn update
        }
        __syncthreads();

        if (step == SS - 1) break;   // last step: s/attn never consumed

        // ---------- y partials over owned rows (W stays L1-resident) ----------
        {
            const int k = t & 63;
            const int g = t >> 6;    // 0..7
            float p = 0.f;
#pragma unroll
            for (int j = 0; j < 4; ++j) {
                int r = g * 4 + j;
                p = fmaf(x_own[r], W[(wgi * NPW + r) * SS + k], p);
            }
            yred[g * SS + k] = p;
        }
        __syncthreads();
        if (t < SS) {
            float yp = 0.f;
#pragma unroll
            for (int g2 = 0; g2 < 8; ++g2) yp += yred[g2 * SS + t];
            y_part[(b * WGPB + wgi) * SS + t] = yp;
        }

        // ---------- barrier B1 (batch scope, release y_part) ----------
        __syncthreads();
        bar += WGPB;
        if (t == 0) {
            __hip_atomic_fetch_add(&cnt[b], 1u, __ATOMIC_RELEASE, __HIP_MEMORY_SCOPE_AGENT);
            while (__hip_atomic_load(&cnt[b], __ATOMIC_ACQUIRE, __HIP_MEMORY_SCOPE_AGENT) < bar)
                __builtin_amdgcn_s_sleep(1);
        }
        __syncthreads();

        // ---------- phase B: assemble y, E_y = exp(2y) ----------
        if (t < SS) {
            float y = bias[t];
#pragma unroll
            for (int w2 = 0; w2 < WGPB; ++w2)
                y += y_part[(b * WGPB + w2) * SS + t];
            ey_lds[t] = __expf(2.0f * y);
        }
        __syncthreads();

        // ---------- heavy: s[b,n] = SCONST - 2 * sum_{s,k} v_k/(Eh*Ey+1) ----------
        // Pair-4 common-denominator: 1/a0+1/a1+1/a2+1/a3 = (n01*d23+n23*d01)/(d01*d23)
        float acc = 0.f;
#pragma unroll 4
        for (int k = 0; k < SS; ++k) {
            float ey = ey_lds[k];
            float a0 = fmaf(eh[0], ey, 1.0f);
            float a1 = fmaf(eh[1], ey, 1.0f);
            float a2 = fmaf(eh[2], ey, 1.0f);
            float a3 = fmaf(eh[3], ey, 1.0f);
            float n01 = a0 + a1, d01 = a0 * a1;
            float n23 = a2 + a3, d23 = a2 * a3;
            float num = fmaf(n01, d23, n23 * d01);
            float r   = rcp_fast(d01 * d23);
            acc = fmaf(v_lds[k], num * r, acc);
        }
#pragma unroll
        for (int off = 1; off < 16; off <<= 1)
            acc += __shfl_xor(acc, off);
        if (sg == 0)
            s_buf[(step & 1) * BB * NN + b * NN + n] = SCONST - 2.0f * acc;

        // ---------- barrier B2 (release s_buf) ----------
        __syncthreads();
        bar += WGPB;
        if (t == 0) {
            __hip_atomic_fetch_add(&cnt[b], 1u, __ATOMIC_RELEASE, __HIP_MEMORY_SCOPE_AGENT);
            while (__hip_atomic_load(&cnt[b], __ATOMIC_ACQUIRE, __HIP_MEMORY_SCOPE_AGENT) < bar)
                __builtin_amdgcn_s_sleep(1);
        }
        __syncthreads();
    }
}

extern "C" void kernel_launch(void* const* d_in, const int* in_sizes, int n_in,
                              void* d_out, int out_size, void* d_ws, size_t ws_size,
                              hipStream_t stream) {
    const float* gin   = (const float*)d_in[0];
    const float* hid   = (const float*)d_in[1];
    const float* v     = (const float*)d_in[2];
    const float* attn0 = (const float*)d_in[3];
    const float* W     = (const float*)d_in[4];
    const float* bias  = (const float*)d_in[5];
    float* out = (float*)d_out;

    unsigned int* cnt = (unsigned int*)d_ws;                       // 32 u32
    float* s_buf  = (float*)((char*)d_ws + 256);                   // 2*B*N f32 = 128 KB
    float* y_part = (float*)((char*)d_ws + 256 + 2 * BB * NN * 4); // B*16*64 f32 = 128 KB

    // barrier counters must start at 0 (d_ws is poisoned 0xAA each launch)
    hipMemsetAsync(d_ws, 0, 256, stream);

    void* args[] = { (void*)&gin, (void*)&hid, (void*)&v, (void*)&attn0,
                     (void*)&W, (void*)&bias, (void*)&out,
                     (void*)&s_buf, (void*)&y_part, (void*)&cnt };
    hipLaunchCooperativeKernel(reinterpret_cast<void*>(spatial_attn_kernel),
                               dim3(GRID), dim3(TPB), args, 0, stream);
}

// Round 4
// 1038.213 us; speedup vs baseline: 4.8768x; 4.8768x over previous
//
#include <hip/hip_runtime.h>

// Problem constants
#define BB   32    // batch
#define NN   512   // nodes
#define SS   64    // seq len / hidden S
#define WGPB 8     // workgroups per batch
#define TPB  512   // threads per workgroup
#define NPW  64    // n-values owned per workgroup (NN / WGPB)
#define GRID (BB*WGPB)   // 256 blocks -> 1 block/CU, co-residency guaranteed

__device__ __forceinline__ float rcp_fast(float x) { return __builtin_amdgcn_rcpf(x); }

// One-time transpose gin[b][n][s] -> gt[b][s][n] (coalesced both sides via LDS tile)
__global__ void __launch_bounds__(512)
transpose_gin(const float* __restrict__ gin, float* __restrict__ gt) {
    __shared__ float tile[64][65];
    const int b  = blockIdx.x >> 3;
    const int n0 = (blockIdx.x & 7) << 6;
    const int c  = threadIdx.x & 63;
    const int r  = threadIdx.x >> 6;   // 0..7
#pragma unroll
    for (int j = 0; j < 8; ++j) {
        int nl = r * 8 + j;
        tile[nl][c] = gin[b * NN * SS + (n0 + nl) * SS + c];
    }
    __syncthreads();
#pragma unroll
    for (int j = 0; j < 8; ++j) {
        int s = r * 8 + j;
        gt[b * SS * NN + s * NN + n0 + c] = tile[c][s];
    }
}

// Persistent cooperative kernel: whole 64-step scan, ONE inter-WG barrier per step.
// 256 blocks of 512 threads -> 1 block/CU (huge co-residency margin).
// Batch b's 8 WGs are bids {b, b+32, ...} == b (mod 8) -> all on XCD b%8.
__global__ void __launch_bounds__(TPB, 2)
spatial_attn_kernel(const float* __restrict__ gin,    // [B,N,S] (fallback path)
                    const float* __restrict__ gt,     // [B,S,N] transposed (if use_t)
                    int use_t,
                    const float* __restrict__ hid,    // [B,S,N]
                    const float* __restrict__ v,      // [S]
                    const float* __restrict__ attn0,  // [B,N]
                    const float* __restrict__ W,      // [N,S]
                    const float* __restrict__ bias,   // [S]
                    float* __restrict__ out,          // [S,B,N]
                    float* __restrict__ s_buf,        // [2][B][N]
                    unsigned int* __restrict__ cnt)   // [B][32] padded, zeroed
{
    const int wg   = blockIdx.x;
    const int b    = wg & 31;          // batch: all 8 WGs of b on one XCD
    const int wgi  = wg >> 5;          // 0..7
    const int t    = threadIdx.x;
    const int lane = t & 63;
    const int wv   = t >> 6;           // wave 0..7
    const int nl   = t >> 3;           // heavy-phase n-local 0..63
    const int sg   = t & 7;            // heavy-phase s-group 0..7
    const int nh   = wgi * NPW + nl;   // owned n
    const int s0   = sg * 8;           // 8 s-values per thread

    __shared__ float  x_all[NN];       // x for all 512 n
    __shared__ float  yred[8 * SS];
    __shared__ float2 vey[SS];         // .x = v_k, .y = ey_k
    __shared__ float  wred[8], wred2[8];

    // W column cache in registers (step-invariant): thread (wv,lane) holds
    // W[wv*64+j][lane] for j=0..63. Coalesced loads (256B/wave per j).
    float wr[64];
#pragma unroll
    for (int j = 0; j < 64; ++j)
        wr[j] = W[(wv * 64 + j) * SS + lane];

    // Step-invariant E_h = exp(2*H) for owned (n, 8 s-values)
    float eh[8];
#pragma unroll
    for (int j = 0; j < 8; ++j)
        eh[j] = __expf(2.0f * hid[b * SS * NN + (s0 + j) * NN + nh]);

    if (t < SS) vey[t].x = v[t];
    const float bk = (t < SS) ? bias[t] : 0.0f;
    __syncthreads();

    float vsum = 0.f;
#pragma unroll
    for (int k = 0; k < SS; ++k) vsum += vey[k].x;
    const float SCONST = (float)SS * vsum;

    unsigned int* mycnt = cnt + b * 32;   // 128B-padded counter per batch

    for (int step = 0; step < SS; ++step) {
        // ---------- phase A: softmax(prev s) -> a -> x ----------
        float a;
        if (step == 0) {
            a = attn0[b * NN + t];
        } else {
            float sv = s_buf[((step - 1) & 1) * BB * NN + b * NN + t];
            float m = sv;
#pragma unroll
            for (int off = 1; off < 64; off <<= 1)
                m = fmaxf(m, __shfl_xor(m, off));
            if (lane == 0) wred[wv] = m;
            __syncthreads();
            m = wred[0];
#pragma unroll
            for (int w2 = 1; w2 < 8; ++w2) m = fmaxf(m, wred[w2]);
            float e = __expf(sv - m);
            float ss = e;
#pragma unroll
            for (int off = 1; off < 64; off <<= 1)
                ss += __shfl_xor(ss, off);
            if (lane == 0) wred2[wv] = ss;
            __syncthreads();
            float tot = wred2[0];
#pragma unroll
            for (int w2 = 1; w2 < 8; ++w2) tot += wred2[w2];
            a = e / tot;
        }
        float inp = use_t ? gt[b * SS * NN + step * NN + t]
                          : gin[b * NN * SS + t * SS + step];
        float x = a * inp;
        x_all[t] = x;
        if ((t >> 6) == wgi)                       // WG wgi writes n in [wgi*64, wgi*64+64)
            out[step * BB * NN + b * NN + t] = x;  // out = x of this step
        __syncthreads();

        if (step == SS - 1) break;   // last step: s/attn never consumed

        // ---------- y[k] fully local (W in registers, x in LDS) ----------
        {
            float p = 0.f;
            const float4* x4 = (const float4*)(x_all + (wv << 6));
#pragma unroll
            for (int j4 = 0; j4 < 16; ++j4) {
                float4 xv = x4[j4];
                p = fmaf(xv.x, wr[4 * j4 + 0], p);
                p = fmaf(xv.y, wr[4 * j4 + 1], p);
                p = fmaf(xv.z, wr[4 * j4 + 2], p);
                p = fmaf(xv.w, wr[4 * j4 + 3], p);
            }
            yred[wv * SS + lane] = p;
        }
        __syncthreads();
        if (t < SS) {
            float y = bk;
#pragma unroll
            for (int g2 = 0; g2 < 8; ++g2) y += yred[g2 * SS + t];
            vey[t].y = __expf(2.0f * y);
        }
        __syncthreads();

        // ---------- heavy: s[n] = SCONST - 2*sum_{s,k} v_k/(Eh*Ey+1) ----------
        // pair-4 common denominator: 1 rcp per 4 elements
        float acc = 0.f;
#pragma unroll 2
        for (int k = 0; k < SS; ++k) {
            float2 ve = vey[k];
            float q = 0.f;
#pragma unroll
            for (int h = 0; h < 2; ++h) {
                float a0 = fmaf(eh[4 * h + 0], ve.y, 1.0f);
                float a1 = fmaf(eh[4 * h + 1], ve.y, 1.0f);
                float a2 = fmaf(eh[4 * h + 2], ve.y, 1.0f);
                float a3 = fmaf(eh[4 * h + 3], ve.y, 1.0f);
                float n01 = a0 + a1, d01 = a0 * a1;
                float n23 = a2 + a3, d23 = a2 * a3;
                float num = fmaf(n01, d23, n23 * d01);
                float r   = rcp_fast(d01 * d23);
                q = fmaf(num, r, q);
            }
            acc = fmaf(ve.x, q, acc);
        }
#pragma unroll
        for (int off = 1; off < 8; off <<= 1)
            acc += __shfl_xor(acc, off);
        if (sg == 0)
            s_buf[(step & 1) * BB * NN + b * NN + nh] = SCONST - 2.0f * acc;

        // ---------- single per-batch barrier (XCD-local, acquire polls) ----------
        __syncthreads();
        if (t == 0) {
            __hip_atomic_fetch_add(mycnt, 1u, __ATOMIC_RELEASE, __HIP_MEMORY_SCOPE_AGENT);
            const unsigned int tgt = (unsigned int)(step + 1) * WGPB;
            while (__hip_atomic_load(mycnt, __ATOMIC_ACQUIRE, __HIP_MEMORY_SCOPE_AGENT) < tgt)
                __builtin_amdgcn_s_sleep(1);
        }
        __syncthreads();
    }
}

extern "C" void kernel_launch(void* const* d_in, const int* in_sizes, int n_in,
                              void* d_out, int out_size, void* d_ws, size_t ws_size,
                              hipStream_t stream) {
    const float* gin   = (const float*)d_in[0];
    const float* hid   = (const float*)d_in[1];
    const float* v     = (const float*)d_in[2];
    const float* attn0 = (const float*)d_in[3];
    const float* W     = (const float*)d_in[4];
    const float* bias  = (const float*)d_in[5];
    float* out = (float*)d_out;

    // ws layout: [0,4K) padded counters | [4K, 4K+128K) s_buf | [+] gin_t (4MB)
    unsigned int* cnt = (unsigned int*)d_ws;
    float* s_buf = (float*)((char*)d_ws + 4096);
    size_t need_t = 4096 + (size_t)2 * BB * NN * 4 + (size_t)BB * NN * SS * 4;
    float* gt = (float*)((char*)d_ws + 4096 + 2 * BB * NN * 4);
    int use_t = (ws_size >= need_t) ? 1 : 0;

    hipMemsetAsync(d_ws, 0, 4096, stream);   // counters to 0 (ws is poisoned 0xAA)
    if (use_t)
        transpose_gin<<<dim3(BB * 8), dim3(512), 0, stream>>>(gin, gt);
    else
        gt = (float*)gin;

    void* args[] = { (void*)&gin, (void*)&gt, (void*)&use_t, (void*)&hid, (void*)&v,
                     (void*)&attn0, (void*)&W, (void*)&bias, (void*)&out,
                     (void*)&s_buf, (void*)&cnt };
    hipLaunchCooperativeKernel(reinterpret_cast<void*>(spatial_attn_kernel),
                               dim3(GRID), dim3(TPB), args, 0, stream);
}

// Round 5
// 1026.553 us; speedup vs baseline: 4.9322x; 1.0114x over previous
//
#include <hip/hip_runtime.h>

// Problem constants
#define BB   32    // batch
#define NN   512   // nodes
#define SS   64    // seq len / hidden S
#define WGPB 8     // workgroups per batch
#define TPB  1024  // threads per workgroup (16 waves -> 4 waves/SIMD at 1 block/CU)
#define NPW  64    // n-values owned per workgroup (NN / WGPB)
#define GRID (BB*WGPB)   // 256 blocks -> 1 block/CU, co-residency guaranteed

__device__ __forceinline__ float rcp_fast(float x) { return __builtin_amdgcn_rcpf(x); }

// One-time transpose gin[b][n][s] -> gt[b][s][n] (coalesced both sides via LDS tile)
__global__ void __launch_bounds__(512)
transpose_gin(const float* __restrict__ gin, float* __restrict__ gt) {
    __shared__ float tile[64][65];
    const int b  = blockIdx.x >> 3;
    const int n0 = (blockIdx.x & 7) << 6;
    const int c  = threadIdx.x & 63;
    const int r  = threadIdx.x >> 6;   // 0..7
#pragma unroll
    for (int j = 0; j < 8; ++j) {
        int nl = r * 8 + j;
        tile[nl][c] = gin[b * NN * SS + (n0 + nl) * SS + c];
    }
    __syncthreads();
#pragma unroll
    for (int j = 0; j < 8; ++j) {
        int s = r * 8 + j;
        gt[b * SS * NN + s * NN + n0 + c] = tile[c][s];
    }
}

// Persistent cooperative kernel: whole 64-step scan, ONE inter-WG barrier per step.
// 256 blocks of 1024 threads -> 1 block/CU, 4 waves/SIMD.
// Batch b's 8 WGs are bids {b, b+32, ...} == b (mod 8) -> all on XCD b%8.
__global__ void __launch_bounds__(TPB, 4)
spatial_attn_kernel(const float* __restrict__ gin,    // [B,N,S] (fallback path)
                    const float* __restrict__ gt,     // [B,S,N] transposed (if use_t)
                    int use_t,
                    const float* __restrict__ hid,    // [B,S,N]
                    const float* __restrict__ v,      // [S]
                    const float* __restrict__ attn0,  // [B,N]
                    const float* __restrict__ W,      // [N,S]
                    const float* __restrict__ bias,   // [S]
                    float* __restrict__ out,          // [S,B,N]
                    float* __restrict__ s_buf,        // [2][B][N]
                    unsigned int* __restrict__ cnt)   // [B][32] padded, zeroed
{
    const int wg   = blockIdx.x;
    const int b    = wg & 31;          // batch: all 8 WGs of b on one XCD
    const int wgi  = wg >> 5;          // 0..7
    const int t    = threadIdx.x;      // 0..1023
    const int lane = t & 63;
    const int wv   = t >> 6;           // wave 0..15
    const int ns   = t & 511;          // softmax-phase n (waves 8..15 alias 0..7)
    const int nl   = t >> 4;           // heavy-phase n-local 0..63
    const int sg   = t & 15;           // heavy-phase s-group 0..15
    const int nh   = wgi * NPW + nl;   // owned n
    const int s0   = sg * 4;           // 4 s-values per thread

    __shared__ float  x_all[NN];         // x for all 512 n
    __shared__ float  yred[16 * SS];
    __shared__ float2 vey[SS];           // .x = v_k, .y = ey_k
    __shared__ float  wred[16], wred2[16];

    // W row cache in registers (step-invariant): thread (wv,lane) holds
    // W[wv*32+j][lane] for j=0..31. Coalesced loads (256B/wave per j).
    float wr[32];
#pragma unroll
    for (int j = 0; j < 32; ++j)
        wr[j] = W[(wv * 32 + j) * SS + lane];

    // Step-invariant E_h = exp(2*H) for owned (n, 4 s-values)
    float eh[4];
#pragma unroll
    for (int j = 0; j < 4; ++j)
        eh[j] = __expf(2.0f * hid[b * SS * NN + (s0 + j) * NN + nh]);

    if (t < SS) vey[t].x = v[t];
    const float bk = (t < SS) ? bias[t] : 0.0f;
    __syncthreads();

    float vsum = 0.f;
#pragma unroll
    for (int k = 0; k < SS; ++k) vsum += vey[k].x;
    const float SCONST = (float)SS * vsum;

    unsigned int* mycnt = cnt + b * 32;   // 128B-padded counter per batch

    for (int step = 0; step < SS; ++step) {
        // ---------- phase A: softmax(prev s) -> a -> x ----------
        // All 16 waves run this uniformly (waves 8..15 duplicate n = t&511);
        // only waves 0..7 write wred/wred2/x_all/out.
        float a;
        if (step == 0) {
            a = attn0[b * NN + ns];
        } else {
            float sv = s_buf[((step - 1) & 1) * BB * NN + b * NN + ns];
            float m = sv;
#pragma unroll
            for (int off = 1; off < 64; off <<= 1)
                m = fmaxf(m, __shfl_xor(m, off));
            if (lane == 0 && wv < 8) wred[wv] = m;
            __syncthreads();
            m = wred[0];
#pragma unroll
            for (int w2 = 1; w2 < 8; ++w2) m = fmaxf(m, wred[w2]);
            float e = __expf(sv - m);
            float ss = e;
#pragma unroll
            for (int off = 1; off < 64; off <<= 1)
                ss += __shfl_xor(ss, off);
            if (lane == 0 && wv < 8) wred2[wv] = ss;
            __syncthreads();
            float tot = wred2[0];
#pragma unroll
            for (int w2 = 1; w2 < 8; ++w2) tot += wred2[w2];
            a = e / tot;
        }
        if (t < NN) {
            float inp = use_t ? gt[b * SS * NN + step * NN + t]
                              : gin[b * NN * SS + t * SS + step];
            float x = a * inp;
            x_all[t] = x;
            if ((t >> 6) == wgi)                       // owned 64-chunk of n
                out[step * BB * NN + b * NN + t] = x;  // out = x of this step
        }
        __syncthreads();

        if (step == SS - 1) break;   // last step: s/attn never consumed

        // ---------- y[k] fully local (W rows in registers, x in LDS) ----------
        {
            float p = 0.f;
            const float4* x4 = (const float4*)(x_all + (wv << 5));
#pragma unroll
            for (int j4 = 0; j4 < 8; ++j4) {
                float4 xv = x4[j4];
                p = fmaf(xv.x, wr[4 * j4 + 0], p);
                p = fmaf(xv.y, wr[4 * j4 + 1], p);
                p = fmaf(xv.z, wr[4 * j4 + 2], p);
                p = fmaf(xv.w, wr[4 * j4 + 3], p);
            }
            yred[wv * SS + lane] = p;
        }
        __syncthreads();
        if (t < SS) {
            float y = bk;
#pragma unroll
            for (int g2 = 0; g2 < 16; ++g2) y += yred[g2 * SS + t];
            vey[t].y = __expf(2.0f * y);
        }
        __syncthreads();

        // ---------- heavy: s[n] = SCONST - 2*sum_{s,k} v_k/(Eh*Ey+1) ----------
        // pair-4 common denominator: 1 rcp per 4 elements
        float acc = 0.f;
#pragma unroll 4
        for (int k = 0; k < SS; ++k) {
            float2 ve = vey[k];
            float a0 = fmaf(eh[0], ve.y, 1.0f);
            float a1 = fmaf(eh[1], ve.y, 1.0f);
            float a2 = fmaf(eh[2], ve.y, 1.0f);
            float a3 = fmaf(eh[3], ve.y, 1.0f);
            float n01 = a0 + a1, d01 = a0 * a1;
            float n23 = a2 + a3, d23 = a2 * a3;
            float num = fmaf(n01, d23, n23 * d01);
            float r   = rcp_fast(d01 * d23);
            acc = fmaf(ve.x, num * r, acc);
        }
#pragma unroll
        for (int off = 1; off < 16; off <<= 1)
            acc += __shfl_xor(acc, off);
        if (sg == 0)
            s_buf[(step & 1) * BB * NN + b * NN + nh] = SCONST - 2.0f * acc;

        // ---------- single per-batch barrier (XCD-local, acquire polls) ----------
        __syncthreads();
        if (t == 0) {
            __hip_atomic_fetch_add(mycnt, 1u, __ATOMIC_RELEASE, __HIP_MEMORY_SCOPE_AGENT);
            const unsigned int tgt = (unsigned int)(step + 1) * WGPB;
            while (__hip_atomic_load(mycnt, __ATOMIC_ACQUIRE, __HIP_MEMORY_SCOPE_AGENT) < tgt)
                __builtin_amdgcn_s_sleep(1);
        }
        __syncthreads();
    }
}

extern "C" void kernel_launch(void* const* d_in, const int* in_sizes, int n_in,
                              void* d_out, int out_size, void* d_ws, size_t ws_size,
                              hipStream_t stream) {
    const float* gin   = (const float*)d_in[0];
    const float* hid   = (const float*)d_in[1];
    const float* v     = (const float*)d_in[2];
    const float* attn0 = (const float*)d_in[3];
    const float* W     = (const float*)d_in[4];
    const float* bias  = (const float*)d_in[5];
    float* out = (float*)d_out;

    // ws layout: [0,4K) padded counters | [4K, 4K+128K) s_buf | [+] gin_t (4MB)
    unsigned int* cnt = (unsigned int*)d_ws;
    float* s_buf = (float*)((char*)d_ws + 4096);
    size_t need_t = 4096 + (size_t)2 * BB * NN * 4 + (size_t)BB * NN * SS * 4;
    float* gt = (float*)((char*)d_ws + 4096 + 2 * BB * NN * 4);
    int use_t = (ws_size >= need_t) ? 1 : 0;

    hipMemsetAsync(d_ws, 0, 4096, stream);   // counters to 0 (ws is poisoned 0xAA)
    if (use_t)
        transpose_gin<<<dim3(BB * 8), dim3(512), 0, stream>>>(gin, gt);
    else
        gt = (float*)gin;

    void* args[] = { (void*)&gin, (void*)&gt, (void*)&use_t, (void*)&hid, (void*)&v,
                     (void*)&attn0, (void*)&W, (void*)&bias, (void*)&out,
                     (void*)&s_buf, (void*)&cnt };
    hipLaunchCooperativeKernel(reinterpret_cast<void*>(spatial_attn_kernel),
                               dim3(GRID), dim3(TPB), args, 0, stream);
}

// Round 6
// 852.035 us; speedup vs baseline: 5.9424x; 1.2048x over previous
//
#include <hip/hip_runtime.h>

// Problem constants
#define BB   32    // batch
#define NN   512   // nodes
#define SS   64    // seq len / hidden S
#define WGPB 8     // workgroups per batch
#define TPB  1024  // threads per workgroup (16 waves -> 4 waves/SIMD at 1 block/CU)
#define NPW  64    // n-values owned per workgroup (NN / WGPB)
#define GRID (BB*WGPB)   // 256 blocks -> 1 block/CU, co-residency guaranteed

__device__ __forceinline__ float rcp_fast(float x) { return __builtin_amdgcn_rcpf(x); }

// One-time transpose gin[b][n][s] -> gt[b][s][n] (coalesced both sides via LDS tile)
__global__ void __launch_bounds__(512)
transpose_gin(const float* __restrict__ gin, float* __restrict__ gt) {
    __shared__ float tile[64][65];
    const int b  = blockIdx.x >> 3;
    const int n0 = (blockIdx.x & 7) << 6;
    const int c  = threadIdx.x & 63;
    const int r  = threadIdx.x >> 6;   // 0..7
#pragma unroll
    for (int j = 0; j < 8; ++j) {
        int nl = r * 8 + j;
        tile[nl][c] = gin[b * NN * SS + (n0 + nl) * SS + c];
    }
    __syncthreads();
#pragma unroll
    for (int j = 0; j < 8; ++j) {
        int s = r * 8 + j;
        gt[b * SS * NN + s * NN + n0 + c] = tile[c][s];
    }
}

// Persistent cooperative kernel. Per step, each WG publishes its 64-n chunk as
// UNNORMALIZED xu = e^{s-m_c} * inp_next plus (m_c, S_c); consumers combine via
// flash-style rescale. All exchange traffic uses agent-scope relaxed atomics
// (coherence-point ops, no cache-wide acquire/release fences).
__global__ void __launch_bounds__(TPB, 4)
spatial_attn_kernel(const float* __restrict__ gin,    // [B,N,S] (fallback path)
                    const float* __restrict__ gt,     // [B,S,N] transposed (if use_t)
                    int use_t,
                    const float* __restrict__ hid,    // [B,S,N]
                    const float* __restrict__ v,      // [S]
                    const float* __restrict__ attn0,  // [B,N]
                    const float* __restrict__ W,      // [N,S]
                    const float* __restrict__ bias,   // [S]
                    float* __restrict__ out,          // [S,B,N]
                    float* __restrict__ xbuf,         // [2][B][N]  xu exchange
                    float* __restrict__ msbuf,        // [2][B][16] (8 m_c, 8 S_c)
                    unsigned int* __restrict__ cnt)   // [B][32] padded, zeroed
{
    const int wg   = blockIdx.x;
    const int b    = wg & 31;          // batch: all 8 WGs of b on one XCD (bid%8)
    const int wgi  = wg >> 5;          // 0..7
    const int t    = threadIdx.x;      // 0..1023
    const int lane = t & 63;
    const int wv   = t >> 6;           // wave 0..15
    const int cw   = wv >> 1;          // chunk this wave's W rows belong to
    const int nl   = t >> 4;           // heavy-phase n-local 0..63
    const int sg   = t & 15;           // heavy-phase s-group 0..15
    const int nh   = wgi * NPW + nl;   // owned n
    const int s0   = sg * 4;           // 4 s-values per thread

    __shared__ __align__(16) float x_all[NN];   // xu (or final x at step 0)
    __shared__ float  yred[16 * SS];
    __shared__ float2 vey[SS];                  // .x = v_k, .y = ey_k
    __shared__ float  s_own[NPW];               // own chunk's s values
    __shared__ float  ms_lds[16];               // 8 m_c, 8 S_c

    // W row cache (step-invariant): thread (wv,lane) holds W[wv*32+j][lane].
    float wr[32];
#pragma unroll
    for (int j = 0; j < 32; ++j)
        wr[j] = W[(wv * 32 + j) * SS + lane];

    // Step-invariant E_h = exp(2*H) for owned (n, 4 s-values)
    float eh[4];
#pragma unroll
    for (int j = 0; j < 4; ++j)
        eh[j] = __expf(2.0f * hid[b * SS * NN + (s0 + j) * NN + nh]);

    if (t < SS) vey[t].x = v[t];
    const float bk = (t < SS) ? bias[t] : 0.0f;
    __syncthreads();

    float vsum = 0.f;
#pragma unroll
    for (int k = 0; k < SS; ++k) vsum += vey[k].x;
    const float SCONST = (float)SS * vsum;

    unsigned int* mycnt = cnt + b * 32;   // 128B-padded counter per batch

    for (int step = 0; step < SS; ++step) {
        // ---------- phase A: obtain x (unnormalized for step>=1) ----------
        float scale_w = 1.0f, scale_own = 1.0f;
        if (step == 0) {
            if (t < NN) {
                float inp = use_t ? gt[b * SS * NN + t]
                                  : gin[b * NN * SS + t * SS];
                x_all[t] = attn0[b * NN + t] * inp;
            }
        } else {
            if (t == 0) {
                const unsigned int tgt = (unsigned int)step * WGPB;
                while (__hip_atomic_load(mycnt, __ATOMIC_RELAXED, __HIP_MEMORY_SCOPE_AGENT) < tgt)
                    __builtin_amdgcn_s_sleep(1);
            }
            __syncthreads();
            const int pb = (step - 1) & 1;
            if (t < NN)
                x_all[t] = __hip_atomic_load(&xbuf[(pb * BB + b) * NN + t],
                                             __ATOMIC_RELAXED, __HIP_MEMORY_SCOPE_AGENT);
            if (t < 16)
                ms_lds[t] = __hip_atomic_load(&msbuf[(pb * BB + b) * 16 + t],
                                              __ATOMIC_RELAXED, __HIP_MEMORY_SCOPE_AGENT);
        }
        __syncthreads();
        if (step > 0) {
            // two-level softmax combine: M = max m_c, T = sum e^{m_c-M} S_c
            float M = ms_lds[0];
#pragma unroll
            for (int c = 1; c < 8; ++c) M = fmaxf(M, ms_lds[c]);
            float T = 0.f;
#pragma unroll
            for (int c = 0; c < 8; ++c) T = fmaf(__expf(ms_lds[c] - M), ms_lds[8 + c], T);
            float rT = rcp_fast(T);
            scale_w   = __expf(ms_lds[cw]  - M) * rT;
            scale_own = __expf(ms_lds[wgi] - M) * rT;
        }
        // out = x of this step (own chunk)
        if ((t >> 6) == wgi)
            out[step * BB * NN + b * NN + t] = x_all[t] * scale_own;

        if (step == SS - 1) break;   // last step: s/attn never consumed

        // ---------- y[k] local: p = scale_c * sum xu[n] W[n][k] ----------
        {
            float p = 0.f;
            const float4* x4 = (const float4*)(x_all + (wv << 5));
#pragma unroll
            for (int j4 = 0; j4 < 8; ++j4) {
                float4 xv = x4[j4];
                p = fmaf(xv.x, wr[4 * j4 + 0], p);
                p = fmaf(xv.y, wr[4 * j4 + 1], p);
                p = fmaf(xv.z, wr[4 * j4 + 2], p);
                p = fmaf(xv.w, wr[4 * j4 + 3], p);
            }
            yred[wv * SS + lane] = p * scale_w;
        }
        __syncthreads();
        if (t < SS) {
            float y = bk;
#pragma unroll
            for (int g2 = 0; g2 < 16; ++g2) y += yred[g2 * SS + t];
            vey[t].y = __expf(2.0f * y);
        }
        __syncthreads();

        // ---------- heavy: s[n] = SCONST - 2*sum_{s,k} v_k/(Eh*Ey+1) ----------
        float acc = 0.f;
#pragma unroll 4
        for (int k = 0; k < SS; ++k) {
            float2 ve = vey[k];
            float a0 = fmaf(eh[0], ve.y, 1.0f);
            float a1 = fmaf(eh[1], ve.y, 1.0f);
            float a2 = fmaf(eh[2], ve.y, 1.0f);
            float a3 = fmaf(eh[3], ve.y, 1.0f);
            float n01 = a0 + a1, d01 = a0 * a1;
            float n23 = a2 + a3, d23 = a2 * a3;
            float num = fmaf(n01, d23, n23 * d01);
            float r   = rcp_fast(d01 * d23);
            acc = fmaf(ve.x, num * r, acc);
        }
#pragma unroll
        for (int off = 1; off < 16; off <<= 1)
            acc += __shfl_xor(acc, off);
        if (sg == 0)
            s_own[nl] = SCONST - 2.0f * acc;
        __syncthreads();

        // ---------- publish (wave 0 only): chunk softmax partials + xu ----------
        // All stores below are issued by wave 0; the release fetch-add (also
        // wave 0) drains the wave's vmcnt first, ordering ALL 64 lanes' stores.
        if (t < SS) {
            float sv = s_own[t];
            float m = sv;
#pragma unroll
            for (int off = 1; off < 64; off <<= 1)
                m = fmaxf(m, __shfl_xor(m, off));
            float e = __expf(sv - m);
            float Sc = e;
#pragma unroll
            for (int off = 1; off < 64; off <<= 1)
                Sc += __shfl_xor(Sc, off);
            const int gn = wgi * NPW + t;
            float inp_next = use_t ? gt[b * SS * NN + (step + 1) * NN + gn]
                                   : gin[b * NN * SS + gn * SS + step + 1];
            float xu = e * inp_next;
            const int pb = step & 1;
            __hip_atomic_store(&xbuf[(pb * BB + b) * NN + gn], xu,
                               __ATOMIC_RELAXED, __HIP_MEMORY_SCOPE_AGENT);
            if (t == 0)
                __hip_atomic_store(&msbuf[(pb * BB + b) * 16 + wgi], m,
                                   __ATOMIC_RELAXED, __HIP_MEMORY_SCOPE_AGENT);
            if (t == 1)
                __hip_atomic_store(&msbuf[(pb * BB + b) * 16 + 8 + wgi], Sc,
                                   __ATOMIC_RELAXED, __HIP_MEMORY_SCOPE_AGENT);
        }
        if (t == 0)
            __hip_atomic_fetch_add(mycnt, 1u, __ATOMIC_RELEASE, __HIP_MEMORY_SCOPE_AGENT);
        // no trailing syncthreads needed: next iteration's poll+sync covers it
    }
}

extern "C" void kernel_launch(void* const* d_in, const int* in_sizes, int n_in,
                              void* d_out, int out_size, void* d_ws, size_t ws_size,
                              hipStream_t stream) {
    const float* gin   = (const float*)d_in[0];
    const float* hid   = (const float*)d_in[1];
    const float* v     = (const float*)d_in[2];
    const float* attn0 = (const float*)d_in[3];
    const float* W     = (const float*)d_in[4];
    const float* bias  = (const float*)d_in[5];
    float* out = (float*)d_out;

    // ws layout: [0,4K) counters | [4K,8K) msbuf | [8K,8K+128K) xbuf | gt (4MB)
    unsigned int* cnt = (unsigned int*)d_ws;
    float* msbuf = (float*)((char*)d_ws + 4096);
    float* xbuf  = (float*)((char*)d_ws + 8192);
    float* gt    = (float*)((char*)d_ws + 8192 + 2 * BB * NN * 4);
    size_t need_t = 8192 + (size_t)2 * BB * NN * 4 + (size_t)BB * NN * SS * 4;
    int use_t = (ws_size >= need_t) ? 1 : 0;

    hipMemsetAsync(d_ws, 0, 4096, stream);   // counters to 0 (ws is poisoned 0xAA)
    if (use_t)
        transpose_gin<<<dim3(BB * 8), dim3(512), 0, stream>>>(gin, gt);
    else
        gt = (float*)gin;

    void* args[] = { (void*)&gin, (void*)&gt, (void*)&use_t, (void*)&hid, (void*)&v,
                     (void*)&attn0, (void*)&W, (void*)&bias, (void*)&out,
                     (void*)&xbuf, (void*)&msbuf, (void*)&cnt };
    hipLaunchCooperativeKernel(reinterpret_cast<void*>(spatial_attn_kernel),
                               dim3(GRID), dim3(TPB), args, 0, stream);
}

// Round 7
// 826.052 us; speedup vs baseline: 6.1293x; 1.0315x over previous
//
#include <hip/hip_runtime.h>

// Problem constants
#define BB   32    // batch
#define NN   512   // nodes
#define SS   64    // seq len / hidden S
#define WGPB 8     // workgroups per batch
#define TPB  1024  // threads per workgroup (16 waves -> 4 waves/SIMD at 1 block/CU)
#define NPW  64    // n-values owned per workgroup (NN / WGPB)
#define GRID (BB*WGPB)   // 256 blocks -> 1 block/CU

#define AT_LD(p)    __hip_atomic_load((p), __ATOMIC_RELAXED, __HIP_MEMORY_SCOPE_AGENT)
#define AT_ST(p,x)  __hip_atomic_store((p), (x), __ATOMIC_RELAXED, __HIP_MEMORY_SCOPE_AGENT)

__device__ __forceinline__ float rcp_fast(float x) { return __builtin_amdgcn_rcpf(x); }

// One-time transpose gin[b][n][s] -> gt[b][s][n]
__global__ void __launch_bounds__(512)
transpose_gin(const float* __restrict__ gin, float* __restrict__ gt) {
    __shared__ float tile[64][65];
    const int b  = blockIdx.x >> 3;
    const int n0 = (blockIdx.x & 7) << 6;
    const int c  = threadIdx.x & 63;
    const int r  = threadIdx.x >> 6;
#pragma unroll
    for (int j = 0; j < 8; ++j) {
        int nl = r * 8 + j;
        tile[nl][c] = gin[b * NN * SS + (n0 + nl) * SS + c];
    }
    __syncthreads();
#pragma unroll
    for (int j = 0; j < 8; ++j) {
        int s = r * 8 + j;
        gt[b * SS * NN + s * NN + n0 + c] = tile[c][s];
    }
}

// Persistent cooperative kernel. Producers publish UNNORMALIZED y-partials
// y_c[k] = sum_{n in chunk} e^{s-m_c} * inp_next[n] * W[n,k] plus (m_c, S_c).
// Consumers combine 8 chunk-partials flash-style -> ey in one sync.
// Exchange: relaxed agent atomics (coherence point); per-WG release flag.
__global__ void __launch_bounds__(TPB, 4)
spatial_attn_kernel(const float* __restrict__ gin,    // [B,N,S] fallback
                    const float* __restrict__ gt,     // [B,S,N] transposed
                    int use_t,
                    const float* __restrict__ hid,    // [B,S,N]
                    const float* __restrict__ v,      // [S]
                    const float* __restrict__ attn0,  // [B,N]
                    const float* __restrict__ W,      // [N,S]
                    const float* __restrict__ bias,   // [S]
                    float* __restrict__ out,          // [S,B,N]
                    float* __restrict__ ybuf,         // [2][B][512] y-partials
                    float* __restrict__ msbuf,        // [2][B][16]  (8 m_c, 8 S_c)
                    unsigned int* __restrict__ flags) // [B][8][32] padded, zeroed
{
    const int wg   = blockIdx.x;
    const int b    = wg & 31;          // all 8 WGs of batch b on one XCD (bid%8)
    const int wgi  = wg >> 5;          // 0..7
    const int t    = threadIdx.x;      // 0..1023
    const int lane = t & 63;
    const int wv   = t >> 6;           // wave 0..15
    const int nl   = t >> 4;           // heavy-phase n-local 0..63
    const int sg   = t & 15;           // heavy-phase s-group 0..15
    const int nh   = wgi * NPW + nl;   // owned n (heavy phase)
    const int s0   = sg * 4;           // 4 s-values per thread
    const int gn   = wgi * NPW + lane; // wave0: owned n (publish/out)

    __shared__ float2 vey[SS];         // .x = v_k, .y = ey_k
    __shared__ float  xu_lds[NPW];
    __shared__ float  yred[16 * SS];
    __shared__ float  s_own[NPW];

    // W cache for y_c: wave wv covers rows wv*4..wv*4+3 of own chunk, col=lane
    const float wc0 = W[(wgi * 64 + wv * 4 + 0) * SS + lane];
    const float wc1 = W[(wgi * 64 + wv * 4 + 1) * SS + lane];
    const float wc2 = W[(wgi * 64 + wv * 4 + 2) * SS + lane];
    const float wc3 = W[(wgi * 64 + wv * 4 + 3) * SS + lane];

    // Step-invariant E_h = exp(2*H)
    float eh[4];
#pragma unroll
    for (int j = 0; j < 4; ++j)
        eh[j] = __expf(2.0f * hid[b * SS * NN + (s0 + j) * NN + nh]);

    if (t < SS) vey[t].x = v[t];
    const float bk = (t < SS) ? bias[t] : 0.0f;
    __syncthreads();

    float vsum = 0.f;
#pragma unroll
    for (int k = 0; k < SS; ++k) vsum += vey[k].x;
    const float SCONST = (float)SS * vsum;

    unsigned int* myflag = flags + (b * 8 + wgi) * 32;

    float xu_reg = 0.f;   // wave0: unnormalized x for own n at current step

    // ---------- prologue publish #0: x_0 = attn0*inp_0, m=0, Sc=1/8 ----------
    if (t < SS) {
        float inp0 = use_t ? gt[b * SS * NN + gn] : gin[b * NN * SS + gn * SS];
        xu_reg = attn0[b * NN + gn] * inp0;
        xu_lds[t] = xu_reg;
    }
    __syncthreads();
    {
        float p;
        p = xu_lds[wv * 4 + 0] * wc0;
        p = fmaf(xu_lds[wv * 4 + 1], wc1, p);
        p = fmaf(xu_lds[wv * 4 + 2], wc2, p);
        p = fmaf(xu_lds[wv * 4 + 3], wc3, p);
        yred[wv * SS + lane] = p;
    }
    __syncthreads();
    if (t < SS) {
        float yc = 0.f;
#pragma unroll
        for (int g = 0; g < 16; ++g) yc += yred[g * SS + t];
        AT_ST(&ybuf[b * NN + wgi * 64 + t], yc);          // pb=0
        if (t == 0) AT_ST(&msbuf[b * 16 + wgi], 0.0f);
        if (t == 1) AT_ST(&msbuf[b * 16 + 8 + wgi], 0.125f);
    }
    if (t == 0)
        __hip_atomic_store(myflag, 1u, __ATOMIC_RELEASE, __HIP_MEMORY_SCOPE_AGENT);

    for (int tau = 0; tau < SS; ++tau) {
        const int pb = tau & 1;
        // ---------- wait for all 8 publishes #tau ----------
        if (t == 0) {
            const unsigned int tgt = (unsigned int)(tau + 1);
            for (;;) {
                bool ok = true;
#pragma unroll
                for (int c = 0; c < 8; ++c)
                    ok &= (AT_LD(&flags[(b * 8 + c) * 32]) >= tgt);
                if (ok) break;
                __builtin_amdgcn_s_sleep(1);
            }
        }
        __syncthreads();

        // ---------- wave0: combine partials -> y, ey; write out ----------
        if (t < SS) {
            const float* msp = &msbuf[(pb * BB + b) * 16];
            float mv[8], sc8[8], yp[8];
#pragma unroll
            for (int c = 0; c < 8; ++c) yp[c]  = AT_LD(&ybuf[(pb * BB + b) * NN + c * 64 + t]);
#pragma unroll
            for (int c = 0; c < 8; ++c) mv[c]  = AT_LD(&msp[c]);
#pragma unroll
            for (int c = 0; c < 8; ++c) sc8[c] = AT_LD(&msp[8 + c]);
            float M = mv[0];
#pragma unroll
            for (int c = 1; c < 8; ++c) M = fmaxf(M, mv[c]);
            float T = 0.f;
#pragma unroll
            for (int c = 0; c < 8; ++c) T = fmaf(__expf(mv[c] - M), sc8[c], T);
            float rT = rcp_fast(T);
            float y = bk;
#pragma unroll
            for (int c = 0; c < 8; ++c) y = fmaf(__expf(mv[c] - M) * rT, yp[c], y);
            vey[t].y = __expf(2.0f * y);
            // out for this step, straight from registers
            out[tau * BB * NN + b * NN + gn] = xu_reg * (__expf(mv[wgi] - M) * rT);
        }
        __syncthreads();

        if (tau == SS - 1) break;

        // ---------- heavy: s[n] = SCONST - 2*sum_{s,k} v_k/(Eh*Ey+1) ----------
        float acc = 0.f;
#pragma unroll 4
        for (int k = 0; k < SS; ++k) {
            float2 ve = vey[k];
            float a0 = fmaf(eh[0], ve.y, 1.0f);
            float a1 = fmaf(eh[1], ve.y, 1.0f);
            float a2 = fmaf(eh[2], ve.y, 1.0f);
            float a3 = fmaf(eh[3], ve.y, 1.0f);
            float n01 = a0 + a1, d01 = a0 * a1;
            float n23 = a2 + a3, d23 = a2 * a3;
            float num = fmaf(n01, d23, n23 * d01);
            float r   = rcp_fast(d01 * d23);
            acc = fmaf(ve.x, num * r, acc);
        }
#pragma unroll
        for (int off = 1; off < 16; off <<= 1)
            acc += __shfl_xor(acc, off);
        if (sg == 0)
            s_own[nl] = SCONST - 2.0f * acc;
        __syncthreads();

        // ---------- wave0: chunk softmax partials + xu for NEXT step ----------
        if (t < SS) {
            float sv = s_own[t];
            float m = sv;
#pragma unroll
            for (int off = 1; off < 64; off <<= 1)
                m = fmaxf(m, __shfl_xor(m, off));
            float e = __expf(sv - m);
            float Sc = e;
#pragma unroll
            for (int off = 1; off < 64; off <<= 1)
                Sc += __shfl_xor(Sc, off);
            float inpn = use_t ? gt[b * SS * NN + (tau + 1) * NN + gn]
                               : gin[b * NN * SS + gn * SS + tau + 1];
            xu_reg = e * inpn;
            xu_lds[t] = xu_reg;
            if (t == 0) AT_ST(&msbuf[((pb ^ 1) * BB + b) * 16 + wgi], m);
            if (t == 1) AT_ST(&msbuf[((pb ^ 1) * BB + b) * 16 + 8 + wgi], Sc);
        }
        __syncthreads();

        // ---------- all 16 waves: y_c partial (4 fma each) ----------
        {
            float p;
            p = xu_lds[wv * 4 + 0] * wc0;
            p = fmaf(xu_lds[wv * 4 + 1], wc1, p);
            p = fmaf(xu_lds[wv * 4 + 2], wc2, p);
            p = fmaf(xu_lds[wv * 4 + 3], wc3, p);
            yred[wv * SS + lane] = p;
        }
        __syncthreads();
        if (t < SS) {
            float yc = 0.f;
#pragma unroll
            for (int g = 0; g < 16; ++g) yc += yred[g * SS + t];
            AT_ST(&ybuf[((pb ^ 1) * BB + b) * NN + wgi * 64 + t], yc);
        }
        // release: wave0's ybuf/msbuf stores drain (vmcnt) before flag store
        if (t == 0)
            __hip_atomic_store(myflag, (unsigned int)(tau + 2),
                               __ATOMIC_RELEASE, __HIP_MEMORY_SCOPE_AGENT);
    }
}

extern "C" void kernel_launch(void* const* d_in, const int* in_sizes, int n_in,
                              void* d_out, int out_size, void* d_ws, size_t ws_size,
                              hipStream_t stream) {
    const float* gin   = (const float*)d_in[0];
    const float* hid   = (const float*)d_in[1];
    const float* v     = (const float*)d_in[2];
    const float* attn0 = (const float*)d_in[3];
    const float* W     = (const float*)d_in[4];
    const float* bias  = (const float*)d_in[5];
    float* out = (float*)d_out;

    // ws: [0,32K) flags | [32K,36K) msbuf | [36K,164K) ybuf | [164K,+4M) gt
    unsigned int* flags = (unsigned int*)d_ws;
    float* msbuf = (float*)((char*)d_ws + 32768);
    float* ybuf  = (float*)((char*)d_ws + 36864);
    float* gt    = (float*)((char*)d_ws + 36864 + (size_t)2 * BB * NN * 4);
    size_t need_t = 36864 + (size_t)2 * BB * NN * 4 + (size_t)BB * NN * SS * 4;
    int use_t = (ws_size >= need_t) ? 1 : 0;

    hipMemsetAsync(d_ws, 0, 32768, stream);   // flags to 0 (ws poisoned 0xAA)
    if (use_t)
        transpose_gin<<<dim3(BB * 8), dim3(512), 0, stream>>>(gin, gt);
    else
        gt = (float*)gin;

    void* args[] = { (void*)&gin, (void*)&gt, (void*)&use_t, (void*)&hid, (void*)&v,
                     (void*)&attn0, (void*)&W, (void*)&bias, (void*)&out,
                     (void*)&ybuf, (void*)&msbuf, (void*)&flags };
    hipLaunchCooperativeKernel(reinterpret_cast<void*>(spatial_attn_kernel),
                               dim3(GRID), dim3(TPB), args, 0, stream);
}

// Round 9
// 822.660 us; speedup vs baseline: 6.1546x; 1.0041x over previous
//
#include <hip/hip_runtime.h>

// Problem constants
#define BB   32    // batch
#define NN   512   // nodes
#define SS   64    // seq len / hidden S
#define CPB  16    // chunks per batch
#define NPW  32    // n-values per chunk
#define TPB  1024  // 16 waves: waves 0-7 = half 0 (even batch), 8-15 = half 1 (odd)
#define GRID 256   // 1 block/CU -- launch-safe

#define AT_LD(p)    __hip_atomic_load((p), __ATOMIC_RELAXED, __HIP_MEMORY_SCOPE_AGENT)
#define AT_ST(p,x)  __hip_atomic_store((p), (x), __ATOMIC_RELAXED, __HIP_MEMORY_SCOPE_AGENT)

__device__ __forceinline__ float rcp_fast(float x) { return __builtin_amdgcn_rcpf(x); }

// Intra-block half-barrier: 8 waves of one half arrive (lane0 ds_add), all poll.
__device__ __forceinline__ void half_bar(unsigned int* cnt, unsigned int tgt) {
    if ((threadIdx.x & 63) == 0)
        __hip_atomic_fetch_add(cnt, 1u, __ATOMIC_RELEASE, __HIP_MEMORY_SCOPE_WORKGROUP);
    while (__hip_atomic_load(cnt, __ATOMIC_ACQUIRE, __HIP_MEMORY_SCOPE_WORKGROUP) < tgt)
        __builtin_amdgcn_s_sleep(1);
}

// One-time transpose gin[b][n][s] -> gt[b][s][n]
__global__ void __launch_bounds__(512)
transpose_gin(const float* __restrict__ gin, float* __restrict__ gt) {
    __shared__ float tile[64][65];
    const int b  = blockIdx.x >> 3;
    const int n0 = (blockIdx.x & 7) << 6;
    const int c  = threadIdx.x & 63;
    const int r  = threadIdx.x >> 6;
#pragma unroll
    for (int j = 0; j < 8; ++j) {
        int nl = r * 8 + j;
        tile[nl][c] = gin[b * NN * SS + (n0 + nl) * SS + c];
    }
    __syncthreads();
#pragma unroll
    for (int j = 0; j < 8; ++j) {
        int s = r * 8 + j;
        gt[b * SS * NN + s * NN + n0 + c] = tile[c][s];
    }
}

// Persistent cooperative kernel. Each block hosts TWO independent jobs:
//   half h (waves 8h..8h+7, 512 thr): chunk c of batch b = 2*(bid&15)+h.
// Halves sync independently (LDS half-barriers); while one half waits on its
// batch's cross-CU flags, the other issues heavy VALU work on the same SIMDs.
// Producers publish UNNORMALIZED y-partials + (m_c,S_c); flash-style combine.
__global__ void __launch_bounds__(TPB, 4)
spatial_attn_kernel(const float* __restrict__ gin,    // [B,N,S] fallback
                    const float* __restrict__ gt,     // [B,S,N] transposed
                    int use_t,
                    const float* __restrict__ hid,    // [B,S,N]
                    const float* __restrict__ v,      // [S]
                    const float* __restrict__ attn0,  // [B,N]
                    const float* __restrict__ W,      // [N,S]
                    const float* __restrict__ bias,   // [S]
                    float* __restrict__ out,          // [S,B,N]
                    float* __restrict__ ybuf,         // [2][B][CPB*SS]
                    float* __restrict__ msbuf,        // [2][B][32] (16 m,16 S)
                    unsigned int* __restrict__ flags) // [B][CPB][32] padded
{
    const int bid  = blockIdx.x;
    const int t    = threadIdx.x;      // 0..1023
    const int h    = t >> 9;           // half 0/1
    const int th   = t & 511;          // thread-in-half
    const int lane = t & 63;
    const int w    = (t >> 6) & 7;     // wave-in-half 0..7
    const int b    = ((bid & 15) << 1) + h;   // even batches h0, odd h1
    const int c    = bid >> 4;                // chunk 0..15 (same for both halves)
    const int nl   = th >> 4;          // heavy: n-local 0..31
    const int sg   = th & 15;          // heavy: s-group 0..15
    const int nh   = c * NPW + nl;
    const int s0   = sg * 4;
    const int gn   = c * NPW + th;     // valid th<32

    __shared__ float2 vey[2][SS];          // .x = v_k, .y = ey_k
    __shared__ float  xu_lds[2][NPW];
    __shared__ float  yred[2][8 * SS];
    __shared__ float  s_own[2][NPW];
    __shared__ unsigned int hb[2][16];     // padded half-barrier counters

    if (t < 2) hb[t][0] = 0;
    if (th < SS) vey[h][th].x = v[th];
    const float bk = (th < SS) ? bias[th] : 0.0f;

    // W cache (step-invariant): wave w holds rows w*4..w*4+3 of own chunk
    const float wc0 = W[(c * NPW + w * 4 + 0) * SS + lane];
    const float wc1 = W[(c * NPW + w * 4 + 1) * SS + lane];
    const float wc2 = W[(c * NPW + w * 4 + 2) * SS + lane];
    const float wc3 = W[(c * NPW + w * 4 + 3) * SS + lane];

    // Step-invariant E_h = exp(2*H)
    float eh[4];
#pragma unroll
    for (int j = 0; j < 4; ++j)
        eh[j] = __expf(2.0f * hid[b * SS * NN + (s0 + j) * NN + nh]);

    __syncthreads();   // only block-wide sync (init)

    // stagger half 1 by ~6.5us so the two halves run anti-phased
    if (h == 1) { __builtin_amdgcn_s_sleep(127); __builtin_amdgcn_s_sleep(127); }

    float vsum = 0.f;
#pragma unroll
    for (int k = 0; k < SS; ++k) vsum += vey[h][k].x;
    const float SCONST = (float)SS * vsum;

    unsigned int bt = 0;               // half-barrier target
    float xu_reg = 0.f;

    // ---------- prologue publish #0: xu = attn0*inp0; m=0, Sc=1/16 ----------
    if (th < NPW) {
        float inp0 = use_t ? gt[b * SS * NN + gn] : gin[b * NN * SS + gn * SS];
        xu_reg = attn0[b * NN + gn] * inp0;
        xu_lds[h][th] = xu_reg;
    }
    bt += 8; half_bar(&hb[h][0], bt);
    {
        float p;
        p = xu_lds[h][w * 4 + 0] * wc0;
        p = fmaf(xu_lds[h][w * 4 + 1], wc1, p);
        p = fmaf(xu_lds[h][w * 4 + 2], wc2, p);
        p = fmaf(xu_lds[h][w * 4 + 3], wc3, p);
        yred[h][w * SS + lane] = p;
    }
    bt += 8; half_bar(&hb[h][0], bt);
    if (th < SS) {
        float yc = 0.f;
#pragma unroll
        for (int g = 0; g < 8; ++g) yc += yred[h][g * SS + th];
        AT_ST(&ybuf[b * (CPB * SS) + c * SS + th], yc);        // pb=0
        if (th == 0) AT_ST(&msbuf[b * 32 + c], 0.0f);
        if (th == 1) AT_ST(&msbuf[b * 32 + 16 + c], 1.0f / 16.0f);
    }
    if (th == 0)
        __hip_atomic_store(&flags[(b * CPB + c) * 32], 1u,
                           __ATOMIC_RELEASE, __HIP_MEMORY_SCOPE_AGENT);

    for (int tau = 0; tau < SS; ++tau) {
        const int pb = tau & 1;
        // ---------- own-half flag wait (other half keeps computing) ----------
        if (th == 0) {
            const unsigned int tgt = (unsigned int)(tau + 1);
            for (;;) {
                bool ok = true;
#pragma unroll
                for (int cc = 0; cc < CPB; ++cc)
                    ok &= (AT_LD(&flags[(b * CPB + cc) * 32]) >= tgt);
                if (ok) break;
                __builtin_amdgcn_s_sleep(1);
            }
        }
        // ---------- combine (first wave of half; same wave as poller) ----------
        if (th < SS) {
            const float* msp = &msbuf[(pb * BB + b) * 32];
            const float* ypp = &ybuf[(pb * BB + b) * (CPB * SS)];
            float mv[16], sc[16], yp[16];
#pragma unroll
            for (int cc = 0; cc < 16; ++cc) yp[cc] = AT_LD(&ypp[cc * SS + th]);
#pragma unroll
            for (int cc = 0; cc < 16; ++cc) mv[cc] = AT_LD(&msp[cc]);
#pragma unroll
            for (int cc = 0; cc < 16; ++cc) sc[cc] = AT_LD(&msp[16 + cc]);
            float M = mv[0];
#pragma unroll
            for (int cc = 1; cc < 16; ++cc) M = fmaxf(M, mv[cc]);
            float T = 0.f, yu = 0.f;
#pragma unroll
            for (int cc = 0; cc < 16; ++cc) {
                float e = __expf(mv[cc] - M);
                T  = fmaf(e, sc[cc], T);
                yu = fmaf(e, yp[cc], yu);
            }
            float rT = rcp_fast(T);
            vey[h][th].y = __expf(2.0f * fmaf(yu, rT, bk));
            if (th < NPW) {
                float mo = AT_LD(&msp[c]);   // own chunk's m (no dyn reg index)
                out[tau * BB * NN + b * NN + gn] = xu_reg * (__expf(mo - M) * rT);
            }
        }
        bt += 8; half_bar(&hb[h][0], bt);    // B1: vey ready
        if (tau == SS - 1) break;

        // prefetch next input (hides under heavy loop)
        float inpn = 0.f;
        if (th < NPW)
            inpn = use_t ? gt[b * SS * NN + (tau + 1) * NN + gn]
                         : gin[b * NN * SS + gn * SS + tau + 1];

        // ---------- heavy: s[n] = SCONST - 2*sum_{s,k} v_k/(Eh*Ey+1) ----------
        float acc = 0.f;
#pragma unroll 4
        for (int k = 0; k < SS; ++k) {
            float2 ve = vey[h][k];
            float a0 = fmaf(eh[0], ve.y, 1.0f);
            float a1 = fmaf(eh[1], ve.y, 1.0f);
            float a2 = fmaf(eh[2], ve.y, 1.0f);
            float a3 = fmaf(eh[3], ve.y, 1.0f);
            float n01 = a0 + a1, d01 = a0 * a1;
            float n23 = a2 + a3, d23 = a2 * a3;
            float num = fmaf(n01, d23, n23 * d01);
            float r   = rcp_fast(d01 * d23);
            acc = fmaf(ve.x, num * r, acc);
        }
#pragma unroll
        for (int off = 1; off < 16; off <<= 1)
            acc += __shfl_xor(acc, off);
        if (sg == 0)
            s_own[h][nl] = SCONST - 2.0f * acc;
        bt += 8; half_bar(&hb[h][0], bt);    // B2: s_own ready

        // ---------- chunk softmax partials + xu for NEXT step (th<32) ----------
        if (th < NPW) {
            float sv = s_own[h][th];
            float m = sv;
#pragma unroll
            for (int off = 1; off < 32; off <<= 1)
                m = fmaxf(m, __shfl_xor(m, off));
            float e = __expf(sv - m);
            float Sc = e;
#pragma unroll
            for (int off = 1; off < 32; off <<= 1)
                Sc += __shfl_xor(Sc, off);
            xu_reg = e * inpn;
            xu_lds[h][th] = xu_reg;
            if (th == 0) AT_ST(&msbuf[((pb ^ 1) * BB + b) * 32 + c], m);
            if (th == 1) AT_ST(&msbuf[((pb ^ 1) * BB + b) * 32 + 16 + c], Sc);
        }
        bt += 8; half_bar(&hb[h][0], bt);    // B3: xu ready

        // ---------- all 8 waves: y_c partial ----------
        {
            float p;
            p = xu_lds[h][w * 4 + 0] * wc0;
            p = fmaf(xu_lds[h][w * 4 + 1], wc1, p);
            p = fmaf(xu_lds[h][w * 4 + 2], wc2, p);
            p = fmaf(xu_lds[h][w * 4 + 3], wc3, p);
            yred[h][w * SS + lane] = p;
        }
        bt += 8; half_bar(&hb[h][0], bt);    // B4: yred ready
        if (th < SS) {
            float yc = 0.f;
#pragma unroll
            for (int g = 0; g < 8; ++g) yc += yred[h][g * SS + th];
            AT_ST(&ybuf[((pb ^ 1) * BB + b) * (CPB * SS) + c * SS + th], yc);
        }
        // release: same wave's ybuf/msbuf stores drain before flag store
        if (th == 0)
            __hip_atomic_store(&flags[(b * CPB + c) * 32], (unsigned int)(tau + 2),
                               __ATOMIC_RELEASE, __HIP_MEMORY_SCOPE_AGENT);
    }
}

extern "C" void kernel_launch(void* const* d_in, const int* in_sizes, int n_in,
                              void* d_out, int out_size, void* d_ws, size_t ws_size,
                              hipStream_t stream) {
    const float* gin   = (const float*)d_in[0];
    const float* hid   = (const float*)d_in[1];
    const float* v     = (const float*)d_in[2];
    const float* attn0 = (const float*)d_in[3];
    const float* W     = (const float*)d_in[4];
    const float* bias  = (const float*)d_in[5];
    float* out = (float*)d_out;

    // ws: [0,64K) flags | [64K,72K) msbuf | [72K,328K) ybuf | [328K,+4M) gt
    unsigned int* flags = (unsigned int*)d_ws;
    float* msbuf = (float*)((char*)d_ws + 65536);
    float* ybuf  = (float*)((char*)d_ws + 65536 + 8192);
    float* gt    = (float*)((char*)d_ws + 65536 + 8192 +
                            (size_t)2 * BB * CPB * SS * 4);
    size_t need_t = 65536 + 8192 + (size_t)2 * BB * CPB * SS * 4
                  + (size_t)BB * NN * SS * 4;
    int use_t = (ws_size >= need_t) ? 1 : 0;

    hipMemsetAsync(d_ws, 0, 65536, stream);   // flags to 0 (ws poisoned 0xAA)
    if (use_t)
        transpose_gin<<<dim3(BB * 8), dim3(512), 0, stream>>>(gin, gt);
    else
        gt = (float*)gin;

    void* args[] = { (void*)&gin, (void*)&gt, (void*)&use_t, (void*)&hid, (void*)&v,
                     (void*)&attn0, (void*)&W, (void*)&bias, (void*)&out,
                     (void*)&ybuf, (void*)&msbuf, (void*)&flags };
    hipLaunchCooperativeKernel(reinterpret_cast<void*>(spatial_attn_kernel),
                               dim3(GRID), dim3(TPB), args, 0, stream);
}

// Round 10
// 197.424 us; speedup vs baseline: 25.6460x; 4.1670x over previous
//
#include <hip/hip_runtime.h>

// Problem constants
#define BB   32
#define NN   512
#define SS   64
#define TPB  1024        // 16 waves; one block = one batch
#define P    16          // Chebyshev order
#define YMAX 0.8f        // interpolation interval [-YMAX, YMAX]; |y| <= ~0.52
#define PI_F 3.14159265358979f

__device__ __forceinline__ float rcp_fast(float x) { return __builtin_amdgcn_rcpf(x); }

// One-time transpose gin[b][n][s] -> gt[b][s][n]
__global__ void __launch_bounds__(512)
transpose_gin(const float* __restrict__ gin, float* __restrict__ gt) {
    __shared__ float tile[64][65];
    const int b  = blockIdx.x >> 3;
    const int n0 = (blockIdx.x & 7) << 6;
    const int c  = threadIdx.x & 63;
    const int r  = threadIdx.x >> 6;
#pragma unroll
    for (int j = 0; j < 8; ++j) {
        int nl = r * 8 + j;
        tile[nl][c] = gin[b * NN * SS + (n0 + nl) * SS + c];
    }
    __syncthreads();
#pragma unroll
    for (int j = 0; j < 8; ++j) {
        int s = r * 8 + j;
        gt[b * SS * NN + s * NN + n0 + c] = tile[c][s];
    }
}

// One block per batch; whole 64-step scan intra-block.
// Key identity: s[n] = sum_{s,k} v_k tanh(H[s,n]+y_k) = sum_p c_p[n] * M_p,
//   c_p[n] = Chebyshev coeffs of G_n(y)=sum_s tanh(H[s,n]+y)  (step-invariant),
//   M_p    = sum_k v_k T_p(y_k/YMAX)                           (16 per step).
__global__ void __launch_bounds__(TPB)
spatial_attn_kernel(const float* __restrict__ gin,    // [B,N,S] fallback
                    const float* __restrict__ gt,     // [B,S,N] transposed
                    int use_t,
                    const float* __restrict__ hid,    // [B,S,N]
                    const float* __restrict__ v,      // [S]
                    const float* __restrict__ attn0,  // [B,N]
                    const float* __restrict__ W,      // [N,S]
                    const float* __restrict__ bias,   // [S]
                    float* __restrict__ out)          // [S,B,N]
{
    const int b    = blockIdx.x;
    const int t    = threadIdx.x;      // 0..1023
    const int lane = t & 63;
    const int w    = t >> 6;           // wave 0..15

    __shared__ float x_lds[NN];        // unnormalized x~ (true x at step 0)
    __shared__ float yred[16][SS];     // GEMV partials (scale applied)
    __shared__ float mom[SS][P + 1];   // v_k * T_p staging (padded)
    __shared__ float m_lds[P];         // moments M_p
    __shared__ float ms[8], ss_[8];    // per-softmax-wave m_w, S~_w
    __shared__ float ctab[P * P];      // DCT-II cos * norm
    __shared__ float gscr[P][NN];      // prologue scratch (upper s-half)

    // ---- W register cache: wave w holds rows 32w..32w+31, col = lane ----
    float wr[32];
#pragma unroll
    for (int j = 0; j < 32; ++j)
        wr[j] = W[(w * 32 + j) * SS + lane];

    // ---- DCT table, softmax-state init, v/bias ----
    if (t < P * P) {
        int p = t >> 4, i = t & 15;
        float cs = __cosf(PI_F * (i + 0.5f) * (float)p / (float)P);
        ctab[t] = cs * ((p == 0) ? (1.0f / P) : (2.0f / P));
    }
    if (t < 8) { ms[t] = 0.f; ss_[t] = 0.125f; }   // => M=0, T=1, scales=1
    const float vreg = (t < SS) ? v[t] : 0.f;
    const float bk   = (t < SS) ? bias[t] : 0.f;

    // ---- node constants u_i = tanh(YMAX*cos(pi(i+.5)/P)) (uniform) ----
    float u[P];
#pragma unroll
    for (int i = 0; i < P; ++i) {
        float yi = YMAX * __cosf(PI_F * (i + 0.5f) / (float)P);
        float e  = __expf(2.f * yi);
        u[i] = 1.f - 2.f * rcp_fast(e + 1.f);
    }

    // ---- G_n at nodes: n = t&511 over s-half (t>>9), via addition formula
    //      tanh(H+yi) = (T+u_i)/(1+T*u_i), T = tanh(H) once per (s,n) ----
    const int n  = t & 511;
    const int hs = t >> 9;
    float g[P];
#pragma unroll
    for (int i = 0; i < P; ++i) g[i] = 0.f;
    for (int s = hs * 32; s < hs * 32 + 32; ++s) {
        float H  = hid[b * SS * NN + s * NN + n];   // coalesced row read
        float e2 = __expf(2.f * H);
        float T  = 1.f - 2.f * rcp_fast(e2 + 1.f);
#pragma unroll
        for (int i = 0; i < P; ++i)
            g[i] += (T + u[i]) * rcp_fast(fmaf(T, u[i], 1.f));
    }
    if (hs) {
#pragma unroll
        for (int i = 0; i < P; ++i) gscr[i][n] = g[i];
    }

    // ---- x_0 = attn0 * inp_0 (+ prefetch inp_1) ----
    float xu_reg = 0.f, inp_nxt = 0.f;
    if (t < NN) {
        float inp0 = use_t ? gt[(size_t)b * SS * NN + t]
                           : gin[(size_t)b * NN * SS + t * SS];
        xu_reg = attn0[b * NN + t] * inp0;
        x_lds[t] = xu_reg;
        inp_nxt = use_t ? gt[(size_t)b * SS * NN + NN + t]
                        : gin[(size_t)b * NN * SS + t * SS + 1];
    }
    __syncthreads();   // gscr/ctab/x_lds/ms ready

    // ---- DCT-II: c_p[n] (step-invariant, registers of thread n=t<512) ----
    float c[P];
    if (t < NN) {
#pragma unroll
        for (int i = 0; i < P; ++i) g[i] += gscr[i][n];
#pragma unroll
        for (int p = 0; p < P; ++p) {
            float a = 0.f;
#pragma unroll
            for (int i = 0; i < P; ++i) a = fmaf(ctab[p * P + i], g[i], a);
            c[p] = a;
        }
    }

    // =================== 63 scan steps + epilogue ===================
    for (int tau = 0; tau < SS - 1; ++tau) {
        // scales from (m_w, S~_w):  M = max, T = sum e^{m-M} S~
        float mM = ms[0];
#pragma unroll
        for (int i = 1; i < 8; ++i) mM = fmaxf(mM, ms[i]);
        float Tn = 0.f;
#pragma unroll
        for (int i = 0; i < 8; ++i) Tn = fmaf(__expf(ms[i] - mM), ss_[i], Tn);
        float rT = rcp_fast(Tn);

        // prefetch inp for step tau+2 (used two phases later)
        const int nx = (tau + 2 < SS) ? tau + 2 : SS - 1;
        float inp_pf = 0.f;
        if (t < NN)
            inp_pf = use_t ? gt[(size_t)b * SS * NN + nx * NN + t]
                           : gin[(size_t)b * NN * SS + t * SS + nx];

        // out[tau] = x~ * e^{m_own-M} / T   (coalesced)
        if (t < NN)
            out[(size_t)tau * BB * NN + b * NN + t] =
                xu_reg * (__expf(ms[t >> 6] - mM) * rT);

        // GEMV: yred[w][k] = scale_w * sum_{rows} x~ * W  (all 16 waves)
        {
            float scl = __expf(ms[w >> 1] - mM) * rT;
            float p = 0.f;
#pragma unroll
            for (int j = 0; j < 32; ++j)
                p = fmaf(x_lds[(w << 5) + j], wr[j], p);
            yred[w][lane] = p * scl;
        }
        __syncthreads();   // B1: yred complete

        // wave 0: y_k -> Chebyshev moments M_p (intra-wave LDS, no barrier)
        if (t < SS) {
            float y = bk;
#pragma unroll
            for (int g2 = 0; g2 < 16; ++g2) y += yred[g2][t];
            float yt = y * (1.0f / YMAX);
            yt = fminf(1.f, fmaxf(-1.f, yt));
            float t0 = 1.f, t1 = yt;
            mom[t][0] = vreg;
            mom[t][1] = vreg * yt;
#pragma unroll
            for (int p = 2; p < P; ++p) {
                float t2 = fmaf(2.f * yt, t1, -t0);
                mom[t][p] = vreg * t2;
                t0 = t1; t1 = t2;
            }
            // reduce M_p = sum_k mom[k][p]: lane l: p=l>>2, q=l&3
            const int pp = t >> 2, q = t & 3;
            float a = 0.f;
#pragma unroll
            for (int j = 0; j < 16; ++j) a += mom[q + 4 * j][pp];
            a += __shfl_xor(a, 1);
            a += __shfl_xor(a, 2);
            if (q == 0) m_lds[pp] = a;
        }
        __syncthreads();   // B2: M_p ready

        // s'[n] = sum_p c_p[n] M_p; per-wave softmax partials; publish x~
        if (t < NN) {
            float s = 0.f;
#pragma unroll
            for (int p = 0; p < P; ++p) s = fmaf(c[p], m_lds[p], s);
            float m = s;
#pragma unroll
            for (int off = 1; off < 64; off <<= 1)
                m = fmaxf(m, __shfl_xor(m, off));
            float e = __expf(s - m);
            float S = e;
#pragma unroll
            for (int off = 1; off < 64; off <<= 1)
                S += __shfl_xor(S, off);
            xu_reg = e * inp_nxt;
            x_lds[t] = xu_reg;
            if (lane == 0) ms[t >> 6] = m;
            if (lane == 1) ss_[t >> 6] = S;
        }
        inp_nxt = inp_pf;
        __syncthreads();   // B3: x~/ms/ss ready for next step
    }

    // epilogue: out[63]
    {
        float mM = ms[0];
#pragma unroll
        for (int i = 1; i < 8; ++i) mM = fmaxf(mM, ms[i]);
        float Tn = 0.f;
#pragma unroll
        for (int i = 0; i < 8; ++i) Tn = fmaf(__expf(ms[i] - mM), ss_[i], Tn);
        float rT = rcp_fast(Tn);
        if (t < NN)
            out[(size_t)(SS - 1) * BB * NN + b * NN + t] =
                xu_reg * (__expf(ms[t >> 6] - mM) * rT);
    }
}

extern "C" void kernel_launch(void* const* d_in, const int* in_sizes, int n_in,
                              void* d_out, int out_size, void* d_ws, size_t ws_size,
                              hipStream_t stream) {
    const float* gin   = (const float*)d_in[0];
    const float* hid   = (const float*)d_in[1];
    const float* v     = (const float*)d_in[2];
    const float* attn0 = (const float*)d_in[3];
    const float* W     = (const float*)d_in[4];
    const float* bias  = (const float*)d_in[5];
    float* out = (float*)d_out;

    // ws: gt (4 MB) only
    float* gt = (float*)d_ws;
    size_t need_t = (size_t)BB * NN * SS * 4;
    int use_t = (ws_size >= need_t) ? 1 : 0;

    if (use_t)
        transpose_gin<<<dim3(BB * 8), dim3(512), 0, stream>>>(gin, gt);
    else
        gt = (float*)gin;

    spatial_attn_kernel<<<dim3(BB), dim3(TPB), 0, stream>>>(
        gin, gt, use_t, hid, v, attn0, W, bias, out);
}